// Round 2
// baseline (2119.784 us; speedup 1.0000x reference)
//
#include <hip/hip_runtime.h>
#include <hip/hip_bf16.h>

typedef unsigned short u16;

// ---------------------------------------------------------------------------
// LinkPredictor pipeline (all node tensors bf16 in workspace):
//   Hs = x_drug @ W_src.T       [N,256]
//   Hd = x_prot @ W_dst.T       [N,256]
//   Gs = Hs @ W_gate[:,:256].T  [N,512]
//   Gd = Hd @ W_gate[:,256:].T  [N,512]
//   Bd = Hd @ W_bil[0].T        [N,256]
//   z1[e] = (sigmoid(Gs[s]+Gd[d]+bg) * [Hs[s],Hd[d]]) @ W1.T    (gate fused in A-stage)
//   stats1 -> scale1/shift1 (b1 cancels in BN)
//   z1 <- relu(bn(z1)) @ W2.T   (in-place row-strip GEMM; b2 cancels)
//   stats2 -> scale2/shift2
//   out[e] = dot(relu(bn(z2)),W3)+b3 + dot(Hs[s],Bd[d])+b_bil
// Workspace total ~225 MB.
// ---------------------------------------------------------------------------

__device__ __forceinline__ float b2f(u16 u) {
    union { unsigned u32; float f; } x; x.u32 = ((unsigned)u) << 16; return x.f;
}
__device__ __forceinline__ u16 f2b(float f) {
    union { float f; unsigned u; } x; x.f = f;
    unsigned r = x.u + 0x7fffu + ((x.u >> 16) & 1u);   // RNE
    return (u16)(r >> 16);
}

__global__ __launch_bounds__(256) void zero_kernel(float* p, int n) {
    int i = blockIdx.x * 256 + threadIdx.x;
    if (i < n) p[i] = 0.f;
}

// ---- node GEMM: C[M,Ncols]=A[M,K] @ W[Ncols,K].T, C bf16, 64x64 tile ----
template <typename TA>
__global__ __launch_bounds__(256) void gemm_node(
    const TA* __restrict__ A, int lda,
    const float* __restrict__ W, int ldb,
    u16* __restrict__ C, int ldc,
    int M, int K)
{
    __shared__ __align__(16) float As[16][68];
    __shared__ __align__(16) float Bs[16][68];
    const int t = threadIdx.x;
    const int row0 = blockIdx.y * 64;
    const int col0 = blockIdx.x * 64;
    const int tx = t & 15, ty = t >> 4;
    const int lr = t >> 2, lk = (t & 3) * 4;

    float acc[4][4] = {};

    for (int k0 = 0; k0 < K; k0 += 16) {
        {   // A tile
            float a[4] = {0.f, 0.f, 0.f, 0.f};
            const int gr = row0 + lr;
            if (gr < M) {
                const TA* ap = A + (size_t)gr * lda + k0 + lk;
                if (sizeof(TA) == 4) {
                    float4 v = *(const float4*)ap;
                    a[0] = v.x; a[1] = v.y; a[2] = v.z; a[3] = v.w;
                } else {
                    ushort4 v = *(const ushort4*)ap;
                    a[0] = b2f(v.x); a[1] = b2f(v.y); a[2] = b2f(v.z); a[3] = b2f(v.w);
                }
            }
#pragma unroll
            for (int i = 0; i < 4; ++i) As[lk + i][lr] = a[i];
        }
        {   // B tile: Bs[k][n] = W[(col0+n)*ldb + k0+k]
            const float* wp = W + (size_t)(col0 + lr) * ldb + k0 + lk;
            float4 v = *(const float4*)wp;
            Bs[lk + 0][lr] = v.x; Bs[lk + 1][lr] = v.y;
            Bs[lk + 2][lr] = v.z; Bs[lk + 3][lr] = v.w;
        }
        __syncthreads();
#pragma unroll
        for (int kk = 0; kk < 16; ++kk) {
            float4 av = *(const float4*)&As[kk][ty * 4];
            float4 bv = *(const float4*)&Bs[kk][tx * 4];
            const float a4[4] = {av.x, av.y, av.z, av.w};
            const float b4[4] = {bv.x, bv.y, bv.z, bv.w};
#pragma unroll
            for (int i = 0; i < 4; ++i)
#pragma unroll
                for (int j = 0; j < 4; ++j)
                    acc[i][j] = fmaf(a4[i], b4[j], acc[i][j]);
        }
        __syncthreads();
    }

#pragma unroll
    for (int i = 0; i < 4; ++i) {
        const int r = row0 + ty * 4 + i;
        if (r >= M) continue;
        ushort4 o;
        o.x = f2b(acc[i][0]); o.y = f2b(acc[i][1]);
        o.z = f2b(acc[i][2]); o.w = f2b(acc[i][3]);
        *(ushort4*)(C + (size_t)r * ldc + col0 + tx * 4) = o;
    }
}

// ---- edge row-strip GEMM: 64 rows x 256 cols per block, in-place safe ----
// GATE=true : A row e = sigmoid(Gs[s]+Gd[d]+bg) * [Hs[s],Hd[d]], K=512
// GATE=false: A row e = relu(Ain[e]*scaleK+shiftK) (bf16 in), K=256, C may ==Ain
template <bool GATE>
__global__ __launch_bounds__(256) void strip_gemm(
    const int* __restrict__ ei, int E,
    const u16* __restrict__ Hs, const u16* __restrict__ Hd,
    const u16* __restrict__ Gs, const u16* __restrict__ Gd,
    const float* __restrict__ bg,
    const u16* __restrict__ Ain,
    const float* __restrict__ scaleK, const float* __restrict__ shiftK,
    const float* __restrict__ W, int K,
    u16* __restrict__ C)
{
    __shared__ __align__(16) float As[16][68];
    __shared__ __align__(16) float Bs[16][260];
    __shared__ int ss[64], dd[64];
    const int t = threadIdx.x;
    const int row0 = blockIdx.x * 64;
    if (GATE) {
        if (t < 64) {
            const int e = min(row0 + t, E - 1);
            ss[t] = ei[e]; dd[t] = ei[E + e];
        }
        __syncthreads();
    }
    const int lr = t >> 2, lk = (t & 3) * 4;
    const int rg = t >> 4, cg = t & 15;

    float acc[4][16] = {};

    for (int k0 = 0; k0 < K; k0 += 16) {
        {   // B stage: thread t = W row n=t, 16 k's
            const float* wp = W + (size_t)t * K + k0;
            float4 w0 = *(const float4*)(wp + 0);
            float4 w1 = *(const float4*)(wp + 4);
            float4 w2 = *(const float4*)(wp + 8);
            float4 w3 = *(const float4*)(wp + 12);
            Bs[0][t] = w0.x;  Bs[1][t] = w0.y;  Bs[2][t] = w0.z;  Bs[3][t] = w0.w;
            Bs[4][t] = w1.x;  Bs[5][t] = w1.y;  Bs[6][t] = w1.z;  Bs[7][t] = w1.w;
            Bs[8][t] = w2.x;  Bs[9][t] = w2.y;  Bs[10][t] = w2.z; Bs[11][t] = w2.w;
            Bs[12][t] = w3.x; Bs[13][t] = w3.y; Bs[14][t] = w3.z; Bs[15][t] = w3.w;
        }
        {   // A stage: 64 rows x 16 k's
            float a[4];
            if (GATE) {
                const int s = ss[lr], d = dd[lr];
                ushort4 gv = *(const ushort4*)(Gs + (size_t)s * 512 + k0 + lk);
                ushort4 dv = *(const ushort4*)(Gd + (size_t)d * 512 + k0 + lk);
                ushort4 hv = (k0 < 256)
                    ? *(const ushort4*)(Hs + (size_t)s * 256 + k0 + lk)
                    : *(const ushort4*)(Hd + (size_t)d * 256 + (k0 - 256) + lk);
                float4 bgv = *(const float4*)(bg + k0 + lk);
                const u16 gq[4] = {gv.x, gv.y, gv.z, gv.w};
                const u16 dq[4] = {dv.x, dv.y, dv.z, dv.w};
                const u16 hq[4] = {hv.x, hv.y, hv.z, hv.w};
                const float bq[4] = {bgv.x, bgv.y, bgv.z, bgv.w};
#pragma unroll
                for (int i = 0; i < 4; ++i) {
                    const float x = b2f(gq[i]) + b2f(dq[i]) + bq[i];
                    const float g = 1.f / (1.f + __expf(-x));
                    a[i] = g * b2f(hq[i]);
                }
            } else {
                const int r = min(row0 + lr, E - 1);
                ushort4 av = *(const ushort4*)(Ain + (size_t)r * 256 + k0 + lk);
                const u16 aq[4] = {av.x, av.y, av.z, av.w};
#pragma unroll
                for (int i = 0; i < 4; ++i) {
                    const int k = k0 + lk + i;
                    a[i] = fmaxf(fmaf(b2f(aq[i]), scaleK[k], shiftK[k]), 0.f);
                }
            }
#pragma unroll
            for (int i = 0; i < 4; ++i) As[lk + i][lr] = a[i];
        }
        __syncthreads();
#pragma unroll
        for (int kk = 0; kk < 16; ++kk) {
            float4 av = *(const float4*)&As[kk][rg * 4];
            const float a4[4] = {av.x, av.y, av.z, av.w};
#pragma unroll
            for (int jj = 0; jj < 4; ++jj) {
                float4 bv = *(const float4*)&Bs[kk][cg * 4 + 64 * jj];
                const float b4[4] = {bv.x, bv.y, bv.z, bv.w};
#pragma unroll
                for (int i = 0; i < 4; ++i)
#pragma unroll
                    for (int j = 0; j < 4; ++j)
                        acc[i][jj * 4 + j] = fmaf(a4[i], b4[j], acc[i][jj * 4 + j]);
            }
        }
        __syncthreads();   // also guarantees all A-reads precede C-writes (in-place)
    }

#pragma unroll
    for (int i = 0; i < 4; ++i) {
        const int r = row0 + rg * 4 + i;
        if (r >= E) continue;
#pragma unroll
        for (int jj = 0; jj < 4; ++jj) {
            ushort4 o;
            o.x = f2b(acc[i][jj * 4 + 0]); o.y = f2b(acc[i][jj * 4 + 1]);
            o.z = f2b(acc[i][jj * 4 + 2]); o.w = f2b(acc[i][jj * 4 + 3]);
            *(ushort4*)(C + (size_t)r * 256 + cg * 4 + 64 * jj) = o;
        }
    }
}

// ---- per-channel sum/sumsq of bf16 [M,256] ----
__global__ __launch_bounds__(256) void stats_kernel(
    const u16* __restrict__ Z, int M, float* __restrict__ sums)
{
    const int c = threadIdx.x;
    const int r0 = blockIdx.x * 512;
    const int r1 = min(r0 + 512, M);
    float s = 0.f, ss = 0.f;
    for (int r = r0; r < r1; ++r) {
        const float x = b2f(Z[(size_t)r * 256 + c]);
        s += x; ss = fmaf(x, x, ss);
    }
    atomicAdd(&sums[c], s);
    atomicAdd(&sums[256 + c], ss);
}

__global__ void finalize_kernel(
    const float* __restrict__ sums, const float* __restrict__ g,
    const float* __restrict__ be, int M,
    float* __restrict__ scale, float* __restrict__ shift)
{
    const int c = threadIdx.x;
    const float inv = 1.f / (float)M;
    const float mean = sums[c] * inv;
    const float var  = sums[256 + c] * inv - mean * mean;
    const float sc = g[c] * rsqrtf(var + 1e-5f);
    scale[c] = sc;
    shift[c] = fmaf(-mean, sc, be[c]);
}

// ---- out = dot(relu(bn(z2)),W3)+b3 + dot(Hs[s],Bd[d])+b_bil ----
__global__ __launch_bounds__(256) void final_kernel(
    const u16* __restrict__ Z2,
    const float* __restrict__ scale2, const float* __restrict__ shift2,
    const float* __restrict__ W3, const float* __restrict__ b3,
    const int* __restrict__ ei,
    const u16* __restrict__ Hs, const u16* __restrict__ Bd,
    const float* __restrict__ b_bil,
    float* __restrict__ out, int E)
{
    const int w = threadIdx.x >> 6, lane = threadIdx.x & 63;
    const int e = blockIdx.x * 4 + w;
    if (e >= E) return;
    const int s = ei[e], d = ei[E + e];
    ushort4 zv = *(const ushort4*)(Z2 + (size_t)e * 256 + lane * 4);
    ushort4 hv = *(const ushort4*)(Hs + (size_t)s * 256 + lane * 4);
    ushort4 bv = *(const ushort4*)(Bd + (size_t)d * 256 + lane * 4);
    float4 sc = *(const float4*)(scale2 + lane * 4);
    float4 sh = *(const float4*)(shift2 + lane * 4);
    float4 w3 = *(const float4*)(W3 + lane * 4);
    const u16 zq[4] = {zv.x, zv.y, zv.z, zv.w};
    const u16 hq[4] = {hv.x, hv.y, hv.z, hv.w};
    const u16 bq[4] = {bv.x, bv.y, bv.z, bv.w};
    const float scq[4] = {sc.x, sc.y, sc.z, sc.w};
    const float shq[4] = {sh.x, sh.y, sh.z, sh.w};
    const float wq[4] = {w3.x, w3.y, w3.z, w3.w};
    float acc = 0.f;
#pragma unroll
    for (int i = 0; i < 4; ++i) {
        const float x = fmaxf(fmaf(b2f(zq[i]), scq[i], shq[i]), 0.f);
        acc = fmaf(x, wq[i], acc);
        acc = fmaf(b2f(hq[i]), b2f(bq[i]), acc);
    }
#pragma unroll
    for (int off = 32; off; off >>= 1) acc += __shfl_down(acc, off, 64);
    if (lane == 0) out[e] = acc + b3[0] + b_bil[0];
}

extern "C" void kernel_launch(void* const* d_in, const int* in_sizes, int n_in,
                              void* d_out, int out_size, void* d_ws, size_t ws_size,
                              hipStream_t stream)
{
    const float* x_drug = (const float*)d_in[0];
    const float* x_prot = (const float*)d_in[1];
    const int*   ei     = (const int*)d_in[2];
    const float* W_src  = (const float*)d_in[3];
    const float* W_dst  = (const float*)d_in[4];
    const float* W_gate = (const float*)d_in[5];
    const float* b_gate = (const float*)d_in[6];
    const float* W1     = (const float*)d_in[7];
    const float* g1     = (const float*)d_in[9];
    const float* be1    = (const float*)d_in[10];
    const float* W2     = (const float*)d_in[11];
    const float* g2     = (const float*)d_in[13];
    const float* be2    = (const float*)d_in[14];
    const float* W3     = (const float*)d_in[15];
    const float* b3     = (const float*)d_in[16];
    const float* W_bil  = (const float*)d_in[17];
    const float* b_bil  = (const float*)d_in[18];
    float* out = (float*)d_out;

    const int N = in_sizes[0] / 256;   // 20000
    const int E = in_sizes[2] / 2;     // 300000

    char* w = (char*)d_ws;
    auto alloc = [&](size_t bytes) {
        char* p = w; w += (bytes + 255) & ~(size_t)255; return p;
    };
    u16*   Hs     = (u16*)alloc((size_t)N * 256 * 2);    // 10.24 MB
    u16*   Hd     = (u16*)alloc((size_t)N * 256 * 2);    // 10.24 MB
    u16*   Gs     = (u16*)alloc((size_t)N * 512 * 2);    // 20.48 MB
    u16*   Gd     = (u16*)alloc((size_t)N * 512 * 2);    // 20.48 MB
    u16*   Bd     = (u16*)alloc((size_t)N * 256 * 2);    // 10.24 MB
    u16*   z      = (u16*)alloc((size_t)E * 256 * 2);    // 153.6 MB (z1, then z2 in-place)
    float* sums   = (float*)alloc(1024 * 4);             // stats1 | stats2
    float* scale1 = (float*)alloc(256 * 4);
    float* shift1 = (float*)alloc(256 * 4);
    float* scale2 = (float*)alloc(256 * 4);
    float* shift2 = (float*)alloc(256 * 4);

    zero_kernel<<<4, 256, 0, stream>>>(sums, 1024);

    const int gy_n = (N + 63) / 64;        // 313
    const int gx_e = (E + 63) / 64;        // 4688

    gemm_node<float><<<dim3(4, gy_n), 256, 0, stream>>>(x_drug, 256, W_src, 256, Hs, 256, N, 256);
    gemm_node<float><<<dim3(4, gy_n), 256, 0, stream>>>(x_prot, 512, W_dst, 512, Hd, 256, N, 512);
    gemm_node<u16><<<dim3(8, gy_n), 256, 0, stream>>>(Hs, 256, W_gate,       512, Gs, 512, N, 256);
    gemm_node<u16><<<dim3(8, gy_n), 256, 0, stream>>>(Hd, 256, W_gate + 256, 512, Gd, 512, N, 256);
    gemm_node<u16><<<dim3(4, gy_n), 256, 0, stream>>>(Hd, 256, W_bil, 256, Bd, 256, N, 256);

    // z1 = gated h @ W1.T  (gate fused into A staging)
    strip_gemm<true><<<gx_e, 256, 0, stream>>>(
        ei, E, Hs, Hd, Gs, Gd, b_gate, nullptr, nullptr, nullptr, W1, 512, z);

    stats_kernel<<<(E + 511) / 512, 256, 0, stream>>>(z, E, sums);
    finalize_kernel<<<1, 256, 0, stream>>>(sums, g1, be1, E, scale1, shift1);

    // z2 = relu(bn(z1)) @ W2.T  (in-place)
    strip_gemm<false><<<gx_e, 256, 0, stream>>>(
        ei, E, nullptr, nullptr, nullptr, nullptr, nullptr, z, scale1, shift1, W2, 256, z);

    stats_kernel<<<(E + 511) / 512, 256, 0, stream>>>(z, E, sums + 512);
    finalize_kernel<<<1, 256, 0, stream>>>(sums + 512, g2, be2, E, scale2, shift2);

    final_kernel<<<(E + 3) / 4, 256, 0, stream>>>(
        z, scale2, shift2, W3, b3, ei, Hs, Bd, b_bil, out, E);
}

// Round 4
// 636.618 us; speedup vs baseline: 3.3298x; 3.3298x over previous
//
#include <hip/hip_runtime.h>
#include <hip/hip_bf16.h>

typedef unsigned short u16;
typedef __attribute__((ext_vector_type(8))) short bf16x8;     // MFMA A/B frag (8 bf16)
typedef __attribute__((ext_vector_type(8))) unsigned short us8;
typedef __attribute__((ext_vector_type(4))) float f32x4;      // MFMA C/D frag

// ---------------------------------------------------------------------------
// Pipeline (node-level precompute kills the edge-level gate/bilinear GEMMs):
//   Hs = x_drug @ W_src.T            [N,256]  bf16
//   Hd = x_prot @ W_dst.T            [N,256]
//   Gs = Hs @ W_gate[:,:256].T + bg  [N,512]  (bias folded here)
//   Gd = Hd @ W_gate[:,256:].T       [N,512]
//   Bd = Hd @ W_bil[0].T             [N,256]
//   z1 = (sigmoid(Gs[s]+Gd[d]) * [Hs[s],Hd[d]]) @ W1.T   (gate fused in A-stage)
//        + fused per-column stats (b1 cancels in BN)
//   z2 = relu(bn(z1)) @ W2.T  in-place, + fused stats  (b2 cancels)
//   out = dot(relu(bn(z2)),W3)+b3 + dot(Hs[s],Bd[d])+b_bil
// All GEMMs: one MFMA template, 128x256 tile, BK=64, 4 waves (2x2) of 64x128.
// Round-4 fix: B-stage must write 8 us8 chunks (64 k's), not 4 — round 3 left
// Bs[t][32..63] uninitialized -> absmax 4.6e5.
// ---------------------------------------------------------------------------

__device__ __forceinline__ float b2f(u16 u) {
    union { unsigned u32; float f; } x; x.u32 = ((unsigned)u) << 16; return x.f;
}
__device__ __forceinline__ u16 f2b(float f) {
    union { float f; unsigned u; } x; x.f = f;
    unsigned r = x.u + 0x7fffu + ((x.u >> 16) & 1u);   // RNE
    return (u16)(r >> 16);
}

__global__ __launch_bounds__(256) void zero_kernel(float* p, int n) {
    int i = blockIdx.x * 256 + threadIdx.x;
    if (i < n) p[i] = 0.f;
}

__global__ __launch_bounds__(256) void cvt_kernel(const float* __restrict__ in,
                                                  u16* __restrict__ out, int n4) {
    int i = blockIdx.x * 256 + threadIdx.x;
    const int stride = gridDim.x * 256;
    for (; i < n4; i += stride) {
        float4 v = ((const float4*)in)[i];
        ushort4 o; o.x = f2b(v.x); o.y = f2b(v.y); o.z = f2b(v.z); o.w = f2b(v.w);
        ((ushort4*)out)[i] = o;
    }
}

#define OP_PLAIN  0
#define OP_GATE   1
#define OP_BNRELU 2

// C[M, 256*gridDim.y] = Agen(A)[M,K] @ Wb[N,K].T  (bf16 in, bf16 out)
// Tile: 128 rows x 256 cols, BK=64. 4 waves, wave (wr,wc) owns 64x128.
template <int AOP, bool STATS, bool BIAS>
__global__ __launch_bounds__(256, 2) void mfma_gemm(
    const u16* __restrict__ Ain, int lda,
    const u16* __restrict__ Wb, int ldb,
    u16* __restrict__ C, int ldc,
    int M, int K,
    const int* __restrict__ ei, int E,
    const u16* __restrict__ Gs, const u16* __restrict__ Gd,
    const u16* __restrict__ Hs, const u16* __restrict__ Hd,
    const float* __restrict__ scaleK, const float* __restrict__ shiftK,
    const float* __restrict__ bias,
    float* __restrict__ sums)
{
    __shared__ u16 As[128][72];          // +8 pad: 144B row stride, ~2-way banks
    __shared__ u16 Bs[256][72];
    __shared__ float wsum[2][2][256];    // [s|ss][wr][col]
    __shared__ int sx[128], dx[128];

    const int t = threadIdx.x;
    const int row0 = blockIdx.x * 128;
    const int col0 = blockIdx.y * 256;

    if constexpr (AOP == OP_GATE) {
        if (t < 128) {
            const int e = min(row0 + t, M - 1);
            sx[t] = ei[e]; dx[t] = ei[E + e];
        }
        __syncthreads();
    }

    const int arow = t >> 1;             // 0..127
    const int ks = (t & 1) * 32;         // 0 or 32
    const int agr = min(row0 + arow, M - 1);

    const int w = t >> 6, lane = t & 63;
    const int wr = w >> 1, wc = w & 1;
    const int lrow = lane & 15, lkg = lane >> 4;

    f32x4 acc[4][8] = {};

    for (int k0 = 0; k0 < K; k0 += 64) {
        // ---- stage B: thread t = output col col0+t, 64 k's (8 x us8) ----
        {
            const u16* wp = Wb + (size_t)(col0 + t) * ldb + k0;
#pragma unroll
            for (int q = 0; q < 8; ++q)
                *(us8*)&Bs[t][q * 8] = *(const us8*)(wp + q * 8);
        }
        // ---- stage A: thread pair per row, 32 k's each ----
        if constexpr (AOP == OP_PLAIN) {
            const u16* ap = Ain + (size_t)agr * lda + k0 + ks;
#pragma unroll
            for (int q = 0; q < 4; ++q)
                *(us8*)&As[arow][ks + q * 8] = *(const us8*)(ap + q * 8);
        } else if constexpr (AOP == OP_GATE) {
            const int s = sx[arow], d = dx[arow];
            const u16* gsp = Gs + (size_t)s * 512 + k0 + ks;
            const u16* gdp = Gd + (size_t)d * 512 + k0 + ks;
            const u16* hp = (k0 < 256) ? (Hs + (size_t)s * 256 + k0 + ks)
                                       : (Hd + (size_t)d * 256 + (k0 - 256) + ks);
#pragma unroll
            for (int q = 0; q < 4; ++q) {
                us8 g8 = *(const us8*)(gsp + q * 8);
                us8 d8 = *(const us8*)(gdp + q * 8);
                us8 h8 = *(const us8*)(hp + q * 8);
                us8 o;
#pragma unroll
                for (int j = 0; j < 8; ++j) {
                    const float x = b2f(g8[j]) + b2f(d8[j]);
                    const float g = 1.f / (1.f + __expf(-x));
                    o[j] = f2b(g * b2f(h8[j]));
                }
                *(us8*)&As[arow][ks + q * 8] = o;
            }
        } else {   // OP_BNRELU
            const u16* ap = Ain + (size_t)agr * lda + k0 + ks;
#pragma unroll
            for (int q = 0; q < 4; ++q) {
                us8 a8 = *(const us8*)(ap + q * 8);
                us8 o;
#pragma unroll
                for (int j = 0; j < 8; ++j) {
                    const int k = k0 + ks + q * 8 + j;
                    o[j] = f2b(fmaxf(fmaf(b2f(a8[j]), scaleK[k], shiftK[k]), 0.f));
                }
                *(us8*)&As[arow][ks + q * 8] = o;
            }
        }
        __syncthreads();
        // ---- MFMA: wave (wr,wc) computes 64x128 with 4x8 16x16 frags ----
#pragma unroll
        for (int kk = 0; kk < 64; kk += 32) {
            bf16x8 af[4];
#pragma unroll
            for (int mi = 0; mi < 4; ++mi)
                af[mi] = *(const bf16x8*)&As[wr * 64 + mi * 16 + lrow][kk + lkg * 8];
#pragma unroll
            for (int ni = 0; ni < 8; ++ni) {
                bf16x8 bfr = *(const bf16x8*)&Bs[wc * 128 + ni * 16 + lrow][kk + lkg * 8];
#pragma unroll
                for (int mi = 0; mi < 4; ++mi)
                    acc[mi][ni] = __builtin_amdgcn_mfma_f32_16x16x32_bf16(
                        af[mi], bfr, acc[mi][ni], 0, 0, 0);
            }
        }
        __syncthreads();
    }

    // ---- epilogue: C-write (+bias), fused per-column stats ----
#pragma unroll
    for (int ni = 0; ni < 8; ++ni) {
        const int gcol = col0 + wc * 128 + ni * 16 + lrow;
        const float bv = BIAS ? bias[gcol] : 0.f;
        float s = 0.f, ss = 0.f;
#pragma unroll
        for (int mi = 0; mi < 4; ++mi) {
            f32x4 v = acc[mi][ni];
#pragma unroll
            for (int j = 0; j < 4; ++j) {
                const int grow = row0 + wr * 64 + mi * 16 + lkg * 4 + j;
                const float x = v[j] + bv;
                if (grow < M) {
                    C[(size_t)grow * ldc + gcol] = f2b(x);
                    if (STATS) { s += x; ss = fmaf(x, x, ss); }
                }
            }
        }
        if constexpr (STATS) {
            s  += __shfl_xor(s, 16, 64);  s  += __shfl_xor(s, 32, 64);
            ss += __shfl_xor(ss, 16, 64); ss += __shfl_xor(ss, 32, 64);
            if (lkg == 0) {
                wsum[0][wr][wc * 128 + ni * 16 + lrow] = s;
                wsum[1][wr][wc * 128 + ni * 16 + lrow] = ss;
            }
        }
    }
    if constexpr (STATS) {      // gridDim.y==1 for stats users => col == t
        __syncthreads();
        atomicAdd(&sums[t],       wsum[0][0][t] + wsum[0][1][t]);
        atomicAdd(&sums[256 + t], wsum[1][0][t] + wsum[1][1][t]);
    }
}

__global__ void finalize_kernel(
    const float* __restrict__ sums, const float* __restrict__ g,
    const float* __restrict__ be, int M,
    float* __restrict__ scale, float* __restrict__ shift)
{
    const int c = threadIdx.x;
    const float inv = 1.f / (float)M;
    const float mean = sums[c] * inv;
    const float var  = sums[256 + c] * inv - mean * mean;
    const float sc = g[c] * rsqrtf(var + 1e-5f);
    scale[c] = sc;
    shift[c] = fmaf(-mean, sc, be[c]);
}

// out = dot(relu(bn(z2)),W3)+b3 + dot(Hs[s],Bd[d])+b_bil   (one wave / edge)
__global__ __launch_bounds__(256) void final_kernel(
    const u16* __restrict__ Z2,
    const float* __restrict__ scale2, const float* __restrict__ shift2,
    const float* __restrict__ W3, const float* __restrict__ b3,
    const int* __restrict__ ei,
    const u16* __restrict__ Hs, const u16* __restrict__ Bd,
    const float* __restrict__ b_bil,
    float* __restrict__ out, int E)
{
    const int w = threadIdx.x >> 6, lane = threadIdx.x & 63;
    const int e = blockIdx.x * 4 + w;
    if (e >= E) return;
    const int s = ei[e], d = ei[E + e];
    ushort4 zv = *(const ushort4*)(Z2 + (size_t)e * 256 + lane * 4);
    ushort4 hv = *(const ushort4*)(Hs + (size_t)s * 256 + lane * 4);
    ushort4 bv = *(const ushort4*)(Bd + (size_t)d * 256 + lane * 4);
    float4 sc = *(const float4*)(scale2 + lane * 4);
    float4 sh = *(const float4*)(shift2 + lane * 4);
    float4 w3 = *(const float4*)(W3 + lane * 4);
    const u16 zq[4] = {zv.x, zv.y, zv.z, zv.w};
    const u16 hq[4] = {hv.x, hv.y, hv.z, hv.w};
    const u16 bq[4] = {bv.x, bv.y, bv.z, bv.w};
    const float scq[4] = {sc.x, sc.y, sc.z, sc.w};
    const float shq[4] = {sh.x, sh.y, sh.z, sh.w};
    const float wq[4] = {w3.x, w3.y, w3.z, w3.w};
    float acc = 0.f;
#pragma unroll
    for (int i = 0; i < 4; ++i) {
        const float x = fmaxf(fmaf(b2f(zq[i]), scq[i], shq[i]), 0.f);
        acc = fmaf(x, wq[i], acc);
        acc = fmaf(b2f(hq[i]), b2f(bq[i]), acc);
    }
#pragma unroll
    for (int off = 32; off; off >>= 1) acc += __shfl_down(acc, off, 64);
    if (lane == 0) out[e] = acc + b3[0] + b_bil[0];
}

extern "C" void kernel_launch(void* const* d_in, const int* in_sizes, int n_in,
                              void* d_out, int out_size, void* d_ws, size_t ws_size,
                              hipStream_t stream)
{
    const float* x_drug = (const float*)d_in[0];
    const float* x_prot = (const float*)d_in[1];
    const int*   ei     = (const int*)d_in[2];
    const float* W_src  = (const float*)d_in[3];
    const float* W_dst  = (const float*)d_in[4];
    const float* W_gate = (const float*)d_in[5];
    const float* b_gate = (const float*)d_in[6];
    const float* W1     = (const float*)d_in[7];
    const float* g1     = (const float*)d_in[9];
    const float* be1    = (const float*)d_in[10];
    const float* W2     = (const float*)d_in[11];
    const float* g2     = (const float*)d_in[13];
    const float* be2    = (const float*)d_in[14];
    const float* W3     = (const float*)d_in[15];
    const float* b3     = (const float*)d_in[16];
    const float* W_bil  = (const float*)d_in[17];
    const float* b_bil  = (const float*)d_in[18];
    float* out = (float*)d_out;

    const int N = in_sizes[0] / 256;   // 20000
    const int E = in_sizes[2] / 2;     // 300000

    char* wp_ = (char*)d_ws;
    auto alloc = [&](size_t bytes) {
        char* p = wp_; wp_ += (bytes + 255) & ~(size_t)255; return p;
    };
    u16* xdb    = (u16*)alloc((size_t)N * 256 * 2);
    u16* xpb    = (u16*)alloc((size_t)N * 512 * 2);
    u16* Wsrcb  = (u16*)alloc(256 * 256 * 2);
    u16* Wdstb  = (u16*)alloc(256 * 512 * 2);
    u16* Wgateb = (u16*)alloc(512 * 512 * 2);
    u16* Wbilb  = (u16*)alloc(256 * 256 * 2);
    u16* W1b    = (u16*)alloc(256 * 512 * 2);
    u16* W2b    = (u16*)alloc(256 * 256 * 2);
    u16* Hs     = (u16*)alloc((size_t)N * 256 * 2);
    u16* Hd     = (u16*)alloc((size_t)N * 256 * 2);
    u16* Gs     = (u16*)alloc((size_t)N * 512 * 2);
    u16* Gd     = (u16*)alloc((size_t)N * 512 * 2);
    u16* Bd     = (u16*)alloc((size_t)N * 256 * 2);
    u16* z      = (u16*)alloc((size_t)E * 256 * 2);   // z1, then z2 in-place
    float* sums   = (float*)alloc(1024 * 4);
    float* scale1 = (float*)alloc(256 * 4);
    float* shift1 = (float*)alloc(256 * 4);
    float* scale2 = (float*)alloc(256 * 4);
    float* shift2 = (float*)alloc(256 * 4);

    zero_kernel<<<4, 256, 0, stream>>>(sums, 1024);

    auto cvt = [&](const float* in, u16* o, int n) {
        const int n4 = n / 4;
        cvt_kernel<<<min((n4 + 255) / 256, 2048), 256, 0, stream>>>(in, o, n4);
    };
    cvt(x_drug, xdb, N * 256);
    cvt(x_prot, xpb, N * 512);
    cvt(W_src,  Wsrcb,  256 * 256);
    cvt(W_dst,  Wdstb,  256 * 512);
    cvt(W_gate, Wgateb, 512 * 512);
    cvt(W_bil,  Wbilb,  256 * 256);
    cvt(W1,     W1b,    256 * 512);
    cvt(W2,     W2b,    256 * 256);

    const int mbN = (N + 127) / 128;   // 157
    const int mbE = (E + 127) / 128;   // 2344

#define NULLS nullptr, 0, nullptr, nullptr, nullptr, nullptr
    // node GEMMs
    mfma_gemm<OP_PLAIN, false, false><<<dim3(mbN, 1), 256, 0, stream>>>(
        xdb, 256, Wsrcb, 256, Hs, 256, N, 256, NULLS, nullptr, nullptr, nullptr, nullptr);
    mfma_gemm<OP_PLAIN, false, false><<<dim3(mbN, 1), 256, 0, stream>>>(
        xpb, 512, Wdstb, 512, Hd, 256, N, 512, NULLS, nullptr, nullptr, nullptr, nullptr);
    mfma_gemm<OP_PLAIN, false, true><<<dim3(mbN, 2), 256, 0, stream>>>(
        Hs, 256, Wgateb, 512, Gs, 512, N, 256, NULLS, nullptr, nullptr, b_gate, nullptr);
    mfma_gemm<OP_PLAIN, false, false><<<dim3(mbN, 2), 256, 0, stream>>>(
        Hd, 256, Wgateb + 256, 512, Gd, 512, N, 256, NULLS, nullptr, nullptr, nullptr, nullptr);
    mfma_gemm<OP_PLAIN, false, false><<<dim3(mbN, 1), 256, 0, stream>>>(
        Hd, 256, Wbilb, 256, Bd, 256, N, 256, NULLS, nullptr, nullptr, nullptr, nullptr);

    // z1 = gated h @ W1.T  + fused stats
    mfma_gemm<OP_GATE, true, false><<<dim3(mbE, 1), 256, 0, stream>>>(
        nullptr, 0, W1b, 512, z, 256, E, 512,
        ei, E, Gs, Gd, Hs, Hd, nullptr, nullptr, nullptr, sums);
    finalize_kernel<<<1, 256, 0, stream>>>(sums, g1, be1, E, scale1, shift1);

    // z2 = relu(bn(z1)) @ W2.T  (in-place) + fused stats
    mfma_gemm<OP_BNRELU, true, false><<<dim3(mbE, 1), 256, 0, stream>>>(
        z, 256, W2b, 256, z, 256, E, 256,
        NULLS, scale1, shift1, nullptr, sums + 512);
    finalize_kernel<<<1, 256, 0, stream>>>(sums + 512, g2, be2, E, scale2, shift2);

    final_kernel<<<(E + 3) / 4, 256, 0, stream>>>(
        z, scale2, shift2, W3, b3, ei, Hs, Bd, b_bil, out, E);
#undef NULLS
}

// Round 5
// 588.932 us; speedup vs baseline: 3.5994x; 1.0810x over previous
//
#include <hip/hip_runtime.h>
#include <hip/hip_bf16.h>

typedef unsigned short u16;
typedef __attribute__((ext_vector_type(8))) short bf16x8;     // MFMA A/B frag (8 bf16)
typedef __attribute__((ext_vector_type(8))) unsigned short us8;
typedef __attribute__((ext_vector_type(4))) float f32x4;      // MFMA C/D frag

// ---------------------------------------------------------------------------
// Pipeline:
//   Hs = x_drug @ W_src.T            [N,256]  (f32 A read directly)
//   Hd = x_prot @ W_dst.T            [N,256]
//   Gs = Hs @ W_gate[:,:256].T + bg  [N,512]
//   Gd = Hd @ W_gate[:,256:].T       [N,512]
//   Bd = Hd @ W_bil[0].T             [N,256]
//   z1 = (sigmoid(Gs[s]+Gd[d]) * [Hs[s],Hd[d]]) @ W1.T  + fused stats
//        + fused bilinear dot(Hs[s],Bd[d]) (Hs already gathered here)
//   z2 = relu(bn(z1)) @ W2.T  in-place + fused stats
//   out = dot(relu(bn(z2)),W3) + b3 + bil
// Edge GEMMs: 128x256 tile, BK=32, DOUBLE-BUFFERED LDS, one barrier/iter,
// next-iter global loads issued into regs before MFMA (latency hidden).
// ---------------------------------------------------------------------------

__device__ __forceinline__ float b2f(u16 u) {
    union { unsigned u32; float f; } x; x.u32 = ((unsigned)u) << 16; return x.f;
}
__device__ __forceinline__ u16 f2b(float f) {
    union { float f; unsigned u; } x; x.f = f;
    unsigned r = x.u + 0x7fffu + ((x.u >> 16) & 1u);   // RNE
    return (u16)(r >> 16);
}

__global__ __launch_bounds__(256) void zero_kernel(float* p, int n) {
    int i = blockIdx.x * 256 + threadIdx.x;
    if (i < n) p[i] = 0.f;
}

struct CvtSeg { const float* in; u16* out; int n4; };
struct CvtArr { CvtSeg s[6]; int tot4; };
__global__ __launch_bounds__(256) void cvt_fused(CvtArr ca) {
    int i = blockIdx.x * 256 + threadIdx.x;
    if (i >= ca.tot4) return;
    int k = 0, off = i;
#pragma unroll
    for (int q = 0; q < 6; ++q) {
        if (off < ca.s[q].n4) { k = q; break; }
        off -= ca.s[q].n4;
    }
    float4 v = ((const float4*)ca.s[k].in)[off];
    ushort4 o; o.x = f2b(v.x); o.y = f2b(v.y); o.z = f2b(v.z); o.w = f2b(v.w);
    ((ushort4*)ca.s[k].out)[off] = o;
}

// ------------------------- node GEMMs (desc-driven) -------------------------
struct GDesc {
    const void* A; int lda; int a_f32;
    const u16* W; int ldb;
    u16* C; int ldc;
    int K;
    const float* bias;
};
template <int NY> struct GDescArr { GDesc d[NY]; };

template <int NY>
__global__ __launch_bounds__(256, 2) void mfma_node(GDescArr<NY> da, int M)
{
    const GDesc dd = da.d[blockIdx.y];
    __shared__ u16 As[2][128][40];
    __shared__ u16 Bs[2][256][40];
    const int t = threadIdx.x;
    const int row0 = blockIdx.x * 128;
    const int arow = t >> 1, aks = (t & 1) * 16;
    const int agr = min(row0 + arow, M - 1);
    const int w = t >> 6, lane = t & 63;
    const int wr = w >> 1, wc = w & 1;
    const int lrow = lane & 15, lkg = lane >> 4;
    const int NIT = dd.K >> 5;

    f32x4 acc[4][8] = {};
    us8 ar[2], br[4];
    float4 fr[4];

    auto load_regs = [&](int it) {
        const int k0 = it << 5;
        if (dd.a_f32) {
            const float* ap = (const float*)dd.A + (size_t)agr * dd.lda + k0 + aks;
#pragma unroll
            for (int q = 0; q < 4; ++q) fr[q] = *(const float4*)(ap + q * 4);
        } else {
            const u16* ap = (const u16*)dd.A + (size_t)agr * dd.lda + k0 + aks;
            ar[0] = *(const us8*)ap; ar[1] = *(const us8*)(ap + 8);
        }
        const u16* wp = dd.W + (size_t)t * dd.ldb + k0;
#pragma unroll
        for (int q = 0; q < 4; ++q) br[q] = *(const us8*)(wp + q * 8);
    };
    auto proc_write = [&](int b) {
        if (dd.a_f32) {
#pragma unroll
            for (int q = 0; q < 2; ++q) {
                us8 o;
                const float fq[8] = {fr[q*2].x, fr[q*2].y, fr[q*2].z, fr[q*2].w,
                                     fr[q*2+1].x, fr[q*2+1].y, fr[q*2+1].z, fr[q*2+1].w};
#pragma unroll
                for (int j = 0; j < 8; ++j) o[j] = f2b(fq[j]);
                *(us8*)&As[b][arow][aks + q * 8] = o;
            }
        } else {
            *(us8*)&As[b][arow][aks] = ar[0];
            *(us8*)&As[b][arow][aks + 8] = ar[1];
        }
#pragma unroll
        for (int q = 0; q < 4; ++q) *(us8*)&Bs[b][t][q * 8] = br[q];
    };
    auto do_mfma = [&](int b) {
        bf16x8 af[4];
#pragma unroll
        for (int mi = 0; mi < 4; ++mi)
            af[mi] = *(const bf16x8*)&As[b][wr * 64 + mi * 16 + lrow][lkg * 8];
#pragma unroll
        for (int ni = 0; ni < 8; ++ni) {
            bf16x8 bfr = *(const bf16x8*)&Bs[b][wc * 128 + ni * 16 + lrow][lkg * 8];
#pragma unroll
            for (int mi = 0; mi < 4; ++mi)
                acc[mi][ni] = __builtin_amdgcn_mfma_f32_16x16x32_bf16(
                    af[mi], bfr, acc[mi][ni], 0, 0, 0);
        }
    };

    load_regs(0); proc_write(0); __syncthreads();
    for (int it = 0; it < NIT; ++it) {
        const int cur = it & 1;
        if (it + 1 < NIT) load_regs(it + 1);
        do_mfma(cur);
        if (it + 1 < NIT) proc_write(cur ^ 1);
        __syncthreads();
    }

#pragma unroll
    for (int ni = 0; ni < 8; ++ni) {
        const int gcol = wc * 128 + ni * 16 + lrow;
        const float bv = dd.bias ? dd.bias[gcol] : 0.f;
#pragma unroll
        for (int mi = 0; mi < 4; ++mi) {
            f32x4 v = acc[mi][ni];
#pragma unroll
            for (int j = 0; j < 4; ++j) {
                const int grow = row0 + wr * 64 + mi * 16 + lkg * 4 + j;
                if (grow < M) dd.C[(size_t)grow * dd.ldc + gcol] = f2b(v[j] + bv);
            }
        }
    }
}

// ------------------------- edge GEMMs (z1 / z2) -----------------------------
#define OP_GATE   1
#define OP_BNRELU 2

template <int AOP>
__global__ __launch_bounds__(256, 2) void mfma_edge(
    const u16* __restrict__ Ain,            // z (BNRELU)
    const u16* __restrict__ Wb, int ldb, int K,
    u16* __restrict__ C, int E,
    const int* __restrict__ ei,
    const u16* __restrict__ Gs, const u16* __restrict__ Gd,
    const u16* __restrict__ Hs, const u16* __restrict__ Hd,
    const u16* __restrict__ Bd, const float* __restrict__ b_bil,
    float* __restrict__ bil,
    const float* __restrict__ scaleK, const float* __restrict__ shiftK,
    float* __restrict__ sums)
{
    __shared__ u16 As[2][128][40];
    __shared__ u16 Bs[2][256][40];
    __shared__ float wsum[2][2][256];
    __shared__ int sx[128], dx[128];

    const int t = threadIdx.x;
    const int row0 = blockIdx.x * 128;

    if constexpr (AOP == OP_GATE) {
        if (t < 128) {
            const int e = min(row0 + t, E - 1);
            sx[t] = ei[e]; dx[t] = ei[E + e];
        }
        __syncthreads();
    }

    const int arow = t >> 1, aks = (t & 1) * 16;
    const int agr = min(row0 + arow, E - 1);
    const int w = t >> 6, lane = t & 63;
    const int wr = w >> 1, wc = w & 1;
    const int lrow = lane & 15, lkg = lane >> 4;
    const int NIT = K >> 5;

    f32x4 acc[4][8] = {};
    float bdot = 0.f;
    us8 g1r[2], g2r[2], hr[2], bdr[2], br[4];
    float4 scA[2], scB[2], shA[2], shB[2];

    auto load_regs = [&](int it) {
        const int k0 = it << 5;
        const int kg = k0 + aks;
        if constexpr (AOP == OP_GATE) {
            const int s = sx[arow], d = dx[arow];
            const u16* gsp = Gs + (size_t)s * 512 + kg;
            const u16* gdp = Gd + (size_t)d * 512 + kg;
            g1r[0] = *(const us8*)gsp; g1r[1] = *(const us8*)(gsp + 8);
            g2r[0] = *(const us8*)gdp; g2r[1] = *(const us8*)(gdp + 8);
            const u16* hp = (k0 < 256) ? (Hs + (size_t)s * 256 + kg)
                                       : (Hd + (size_t)d * 256 + kg - 256);
            hr[0] = *(const us8*)hp; hr[1] = *(const us8*)(hp + 8);
            if (k0 < 256) {
                const u16* bp = Bd + (size_t)dx[arow] * 256 + kg;
                bdr[0] = *(const us8*)bp; bdr[1] = *(const us8*)(bp + 8);
            }
        } else {
            const u16* ap = Ain + (size_t)agr * 256 + kg;
            g1r[0] = *(const us8*)ap; g1r[1] = *(const us8*)(ap + 8);
#pragma unroll
            for (int q = 0; q < 2; ++q) {
                scA[q] = *(const float4*)(scaleK + kg + q * 8);
                scB[q] = *(const float4*)(scaleK + kg + q * 8 + 4);
                shA[q] = *(const float4*)(shiftK + kg + q * 8);
                shB[q] = *(const float4*)(shiftK + kg + q * 8 + 4);
            }
        }
        const u16* wp = Wb + (size_t)t * ldb + k0;
#pragma unroll
        for (int q = 0; q < 4; ++q) br[q] = *(const us8*)(wp + q * 8);
    };
    auto proc_write = [&](int it, int b) {
        const int k0 = it << 5;
#pragma unroll
        for (int q = 0; q < 2; ++q) {
            us8 o;
            if constexpr (AOP == OP_GATE) {
#pragma unroll
                for (int j = 0; j < 8; ++j) {
                    const float x = b2f(g1r[q][j]) + b2f(g2r[q][j]);
                    const float g = 1.f / (1.f + __expf(-x));
                    o[j] = f2b(g * b2f(hr[q][j]));
                }
                if (k0 < 256) {
#pragma unroll
                    for (int j = 0; j < 8; ++j)
                        bdot = fmaf(b2f(hr[q][j]), b2f(bdr[q][j]), bdot);
                }
            } else {
                const float scq[8] = {scA[q].x, scA[q].y, scA[q].z, scA[q].w,
                                      scB[q].x, scB[q].y, scB[q].z, scB[q].w};
                const float shq[8] = {shA[q].x, shA[q].y, shA[q].z, shA[q].w,
                                      shB[q].x, shB[q].y, shB[q].z, shB[q].w};
#pragma unroll
                for (int j = 0; j < 8; ++j)
                    o[j] = f2b(fmaxf(fmaf(b2f(g1r[q][j]), scq[j], shq[j]), 0.f));
            }
            *(us8*)&As[b][arow][aks + q * 8] = o;
        }
#pragma unroll
        for (int q = 0; q < 4; ++q) *(us8*)&Bs[b][t][q * 8] = br[q];
    };
    auto do_mfma = [&](int b) {
        bf16x8 af[4];
#pragma unroll
        for (int mi = 0; mi < 4; ++mi)
            af[mi] = *(const bf16x8*)&As[b][wr * 64 + mi * 16 + lrow][lkg * 8];
#pragma unroll
        for (int ni = 0; ni < 8; ++ni) {
            bf16x8 bfr = *(const bf16x8*)&Bs[b][wc * 128 + ni * 16 + lrow][lkg * 8];
#pragma unroll
            for (int mi = 0; mi < 4; ++mi)
                acc[mi][ni] = __builtin_amdgcn_mfma_f32_16x16x32_bf16(
                    af[mi], bfr, acc[mi][ni], 0, 0, 0);
        }
    };

    load_regs(0); proc_write(0, 0); __syncthreads();
    for (int it = 0; it < NIT; ++it) {
        const int cur = it & 1;
        if (it + 1 < NIT) load_regs(it + 1);
        do_mfma(cur);
        if (it + 1 < NIT) proc_write(it + 1, cur ^ 1);
        __syncthreads();
    }

    if constexpr (AOP == OP_GATE) {
        bdot += __shfl_xor(bdot, 1, 64);
        if ((t & 1) == 0 && row0 + arow < E)
            bil[row0 + arow] = bdot + b_bil[0];
    }

    // epilogue: C-write + fused per-column stats
#pragma unroll
    for (int ni = 0; ni < 8; ++ni) {
        const int gcol = wc * 128 + ni * 16 + lrow;
        float s = 0.f, ss = 0.f;
#pragma unroll
        for (int mi = 0; mi < 4; ++mi) {
            f32x4 v = acc[mi][ni];
#pragma unroll
            for (int j = 0; j < 4; ++j) {
                const int grow = row0 + wr * 64 + mi * 16 + lkg * 4 + j;
                const float x = v[j];
                if (grow < E) {
                    C[(size_t)grow * 256 + gcol] = f2b(x);
                    s += x; ss = fmaf(x, x, ss);
                }
            }
        }
        s  += __shfl_xor(s, 16, 64);  s  += __shfl_xor(s, 32, 64);
        ss += __shfl_xor(ss, 16, 64); ss += __shfl_xor(ss, 32, 64);
        if (lkg == 0) {
            wsum[0][wr][gcol] = s;
            wsum[1][wr][gcol] = ss;
        }
    }
    __syncthreads();
    atomicAdd(&sums[t],       wsum[0][0][t] + wsum[0][1][t]);
    atomicAdd(&sums[256 + t], wsum[1][0][t] + wsum[1][1][t]);
}

__global__ void finalize_kernel(
    const float* __restrict__ sums, const float* __restrict__ g,
    const float* __restrict__ be, int M,
    float* __restrict__ scale, float* __restrict__ shift)
{
    const int c = threadIdx.x;
    const float inv = 1.f / (float)M;
    const float mean = sums[c] * inv;
    const float var  = sums[256 + c] * inv - mean * mean;
    const float sc = g[c] * rsqrtf(var + 1e-5f);
    scale[c] = sc;
    shift[c] = fmaf(-mean, sc, be[c]);
}

// out = dot(relu(bn(z2)),W3)+b3 + bil   (one wave / edge; bil from z1 pass)
__global__ __launch_bounds__(256) void final_kernel(
    const u16* __restrict__ Z2,
    const float* __restrict__ scale2, const float* __restrict__ shift2,
    const float* __restrict__ W3, const float* __restrict__ b3,
    const float* __restrict__ bil,
    float* __restrict__ out, int E)
{
    const int w = threadIdx.x >> 6, lane = threadIdx.x & 63;
    const int e = blockIdx.x * 4 + w;
    if (e >= E) return;
    ushort4 zv = *(const ushort4*)(Z2 + (size_t)e * 256 + lane * 4);
    float4 sc = *(const float4*)(scale2 + lane * 4);
    float4 sh = *(const float4*)(shift2 + lane * 4);
    float4 w3 = *(const float4*)(W3 + lane * 4);
    const u16 zq[4] = {zv.x, zv.y, zv.z, zv.w};
    const float scq[4] = {sc.x, sc.y, sc.z, sc.w};
    const float shq[4] = {sh.x, sh.y, sh.z, sh.w};
    const float wq[4] = {w3.x, w3.y, w3.z, w3.w};
    float acc = 0.f;
#pragma unroll
    for (int i = 0; i < 4; ++i) {
        const float x = fmaxf(fmaf(b2f(zq[i]), scq[i], shq[i]), 0.f);
        acc = fmaf(x, wq[i], acc);
    }
#pragma unroll
    for (int off = 32; off; off >>= 1) acc += __shfl_down(acc, off, 64);
    if (lane == 0) out[e] = acc + b3[0] + bil[e];
}

extern "C" void kernel_launch(void* const* d_in, const int* in_sizes, int n_in,
                              void* d_out, int out_size, void* d_ws, size_t ws_size,
                              hipStream_t stream)
{
    const float* x_drug = (const float*)d_in[0];
    const float* x_prot = (const float*)d_in[1];
    const int*   ei     = (const int*)d_in[2];
    const float* W_src  = (const float*)d_in[3];
    const float* W_dst  = (const float*)d_in[4];
    const float* W_gate = (const float*)d_in[5];
    const float* b_gate = (const float*)d_in[6];
    const float* W1     = (const float*)d_in[7];
    const float* g1     = (const float*)d_in[9];
    const float* be1    = (const float*)d_in[10];
    const float* W2     = (const float*)d_in[11];
    const float* g2     = (const float*)d_in[13];
    const float* be2    = (const float*)d_in[14];
    const float* W3     = (const float*)d_in[15];
    const float* b3     = (const float*)d_in[16];
    const float* W_bil  = (const float*)d_in[17];
    const float* b_bil  = (const float*)d_in[18];
    float* out = (float*)d_out;

    const int N = in_sizes[0] / 256;   // 20000
    const int E = in_sizes[2] / 2;     // 300000

    char* wp_ = (char*)d_ws;
    auto alloc = [&](size_t bytes) {
        char* p = wp_; wp_ += (bytes + 255) & ~(size_t)255; return p;
    };
    u16* Wsrcb  = (u16*)alloc(256 * 256 * 2);
    u16* Wdstb  = (u16*)alloc(256 * 512 * 2);
    u16* Wgateb = (u16*)alloc(512 * 512 * 2);
    u16* Wbilb  = (u16*)alloc(256 * 256 * 2);
    u16* W1b    = (u16*)alloc(256 * 512 * 2);
    u16* W2b    = (u16*)alloc(256 * 256 * 2);
    u16* Hs     = (u16*)alloc((size_t)N * 256 * 2);
    u16* Hd     = (u16*)alloc((size_t)N * 256 * 2);
    u16* Gs     = (u16*)alloc((size_t)N * 512 * 2);
    u16* Gd     = (u16*)alloc((size_t)N * 512 * 2);
    u16* Bd     = (u16*)alloc((size_t)N * 256 * 2);
    u16* z      = (u16*)alloc((size_t)E * 256 * 2);   // z1, then z2 in-place
    float* bil  = (float*)alloc((size_t)E * 4);
    float* sums   = (float*)alloc(1024 * 4);
    float* scale1 = (float*)alloc(256 * 4);
    float* shift1 = (float*)alloc(256 * 4);
    float* scale2 = (float*)alloc(256 * 4);
    float* shift2 = (float*)alloc(256 * 4);

    zero_kernel<<<4, 256, 0, stream>>>(sums, 1024);

    // fused weight converts (x inputs read as f32 directly by mfma_node)
    CvtArr ca;
    ca.s[0] = {W_src,  Wsrcb,  256 * 256 / 4};
    ca.s[1] = {W_dst,  Wdstb,  256 * 512 / 4};
    ca.s[2] = {W_gate, Wgateb, 512 * 512 / 4};
    ca.s[3] = {W_bil,  Wbilb,  256 * 256 / 4};
    ca.s[4] = {W1,     W1b,    256 * 512 / 4};
    ca.s[5] = {W2,     W2b,    256 * 256 / 4};
    ca.tot4 = 0;
    for (int q = 0; q < 6; ++q) ca.tot4 += ca.s[q].n4;
    cvt_fused<<<(ca.tot4 + 255) / 256, 256, 0, stream>>>(ca);

    const int gxN = (N + 127) / 128;   // 157
    const int gxE = (E + 127) / 128;   // 2344

    // phase 1: Hs, Hd
    GDescArr<2> p1;
    p1.d[0] = {x_drug, 256, 1, Wsrcb, 256, Hs, 256, 256, nullptr};
    p1.d[1] = {x_prot, 512, 1, Wdstb, 512, Hd, 256, 512, nullptr};
    mfma_node<2><<<dim3(gxN, 2), 256, 0, stream>>>(p1, N);

    // phase 2: Gs (2 tiles, +b_gate), Gd (2 tiles), Bd
    GDescArr<5> p2;
    p2.d[0] = {Hs, 256, 0, Wgateb,                 512, Gs,       512, 256, b_gate};
    p2.d[1] = {Hs, 256, 0, Wgateb + 256 * 512,     512, Gs + 256, 512, 256, b_gate + 256};
    p2.d[2] = {Hd, 256, 0, Wgateb + 256,           512, Gd,       512, 256, nullptr};
    p2.d[3] = {Hd, 256, 0, Wgateb + 256 * 512 + 256, 512, Gd + 256, 512, 256, nullptr};
    p2.d[4] = {Hd, 256, 0, Wbilb,                  256, Bd,       256, 256, nullptr};
    mfma_node<5><<<dim3(gxN, 5), 256, 0, stream>>>(p2, N);

    // z1 = gated h @ W1.T + stats1 + fused bilinear
    mfma_edge<OP_GATE><<<gxE, 256, 0, stream>>>(
        nullptr, W1b, 512, 512, z, E,
        ei, Gs, Gd, Hs, Hd, Bd, b_bil, bil, nullptr, nullptr, sums);
    finalize_kernel<<<1, 256, 0, stream>>>(sums, g1, be1, E, scale1, shift1);

    // z2 = relu(bn(z1)) @ W2.T  (in-place) + stats2
    mfma_edge<OP_BNRELU><<<gxE, 256, 0, stream>>>(
        z, W2b, 256, 256, z, E,
        nullptr, nullptr, nullptr, nullptr, nullptr, nullptr, nullptr, nullptr,
        scale1, shift1, sums + 512);
    finalize_kernel<<<1, 256, 0, stream>>>(sums + 512, g2, be2, E, scale2, shift2);

    final_kernel<<<(E + 3) / 4, 256, 0, stream>>>(
        z, scale2, shift2, W3, b3, bil, out, E);
}